// Round 2
// baseline (3462.475 us; speedup 1.0000x reference)
//
#include <hip/hip_runtime.h>
#include <math.h>

#define TOKENS  16384
#define HIDDEN  4096
#define NEXPERT 256
#define NGROUP  8
#define GSIZE   32
#define TOPKG   4
#define TOPK    8
#define ROUTED_SCALING 2.5f

// ---------------- GEMM (split-K): Cp[z] = A @ B^T over K-half z ----------------
#define BM 128
#define BN 64
#define BK 16
#define LDA 132   // floats; 132%32=4 -> transpose writes are 2-way bank-aliased (free)
#define LDB 68
#define GTHREADS 128

__global__ __launch_bounds__(GTHREADS, 2)
void gemm_part(const float* __restrict__ A,   // [TOKENS, HIDDEN]
               const float* __restrict__ B,   // [NEXPERT, HIDDEN]
               float* __restrict__ Cp,        // [ksplit, TOKENS, NEXPERT]
               int ksplit)
{
    __shared__ float As[2][BK * LDA];   // As[k][m]
    __shared__ float Bs[2][BK * LDB];   // Bs[k][n]

    const int tid = threadIdx.x;
    const int n0  = blockIdx.x * BN;
    const int m0  = blockIdx.y * BM;
    const int z   = blockIdx.z;
    const int kbase = z * (HIDDEN / ksplit);
    const int NKT   = (HIDDEN / ksplit) / BK;

    // compute mapping: 16x8 thread grid, 8x8 micro-tile
    const int tr = tid >> 3;   // 0..15
    const int tc = tid & 7;    // 0..7

    // staging mapping
    const int brow = tid & 63;   // B row within tile
    const int bkh  = tid >> 6;   // 0/1: which 8-k half

    const float* Arow = A + (long)(m0 + tid) * HIDDEN + kbase;          // 16 floats/tile
    const float* Brow = B + (long)(n0 + brow) * HIDDEN + kbase + bkh * 8; // 8 floats/tile

    float4 pa[4];
    float4 pb[2];

    // prefetch tile 0
    pa[0] = *(const float4*)(Arow + 0);
    pa[1] = *(const float4*)(Arow + 4);
    pa[2] = *(const float4*)(Arow + 8);
    pa[3] = *(const float4*)(Arow + 12);
    pb[0] = *(const float4*)(Brow + 0);
    pb[1] = *(const float4*)(Brow + 4);

    // write tile 0 -> buf 0 (transposed; banks 2-way aliased only)
    {
        float* as = As[0];
        #pragma unroll
        for (int q = 0; q < 4; ++q) {
            float* d = as + (q * 4) * LDA + tid;
            d[0 * LDA] = pa[q].x; d[1 * LDA] = pa[q].y;
            d[2 * LDA] = pa[q].z; d[3 * LDA] = pa[q].w;
        }
        float* bs = Bs[0];
        #pragma unroll
        for (int q = 0; q < 2; ++q) {
            float* d = bs + (bkh * 8 + q * 4) * LDB + brow;
            d[0 * LDB] = pb[q].x; d[1 * LDB] = pb[q].y;
            d[2 * LDB] = pb[q].z; d[3 * LDB] = pb[q].w;
        }
    }
    __syncthreads();

    float acc[8][8] = {};

    for (int kt = 0; kt < NKT; ++kt) {
        // global prefetch for next tile (in flight during compute)
        if (kt + 1 < NKT) {
            const float* ar = Arow + (kt + 1) * BK;
            pa[0] = *(const float4*)(ar + 0);
            pa[1] = *(const float4*)(ar + 4);
            pa[2] = *(const float4*)(ar + 8);
            pa[3] = *(const float4*)(ar + 12);
            const float* br = Brow + (kt + 1) * BK;
            pb[0] = *(const float4*)(br + 0);
            pb[1] = *(const float4*)(br + 4);
        }

        // compute from buf[kt&1]; fresh per-tile accumulators for accuracy
        const float* as = As[kt & 1];
        const float* bs = Bs[kt & 1];
        float t_[8][8] = {};
        #pragma unroll
        for (int k = 0; k < BK; ++k) {
            float4 a0 = *(const float4*)(as + k * LDA + tr * 8);
            float4 a1 = *(const float4*)(as + k * LDA + tr * 8 + 4);
            float4 b0 = *(const float4*)(bs + k * LDB + tc * 8);
            float4 b1 = *(const float4*)(bs + k * LDB + tc * 8 + 4);
            float av[8] = {a0.x, a0.y, a0.z, a0.w, a1.x, a1.y, a1.z, a1.w};
            float bv[8] = {b0.x, b0.y, b0.z, b0.w, b1.x, b1.y, b1.z, b1.w};
            #pragma unroll
            for (int i = 0; i < 8; ++i)
                #pragma unroll
                for (int j = 0; j < 8; ++j)
                    t_[i][j] = fmaf(av[i], bv[j], t_[i][j]);
        }
        #pragma unroll
        for (int i = 0; i < 8; ++i)
            #pragma unroll
            for (int j = 0; j < 8; ++j)
                acc[i][j] += t_[i][j];

        // stage next tile into the other buffer
        if (kt + 1 < NKT) {
            float* as_w = As[(kt + 1) & 1];
            #pragma unroll
            for (int q = 0; q < 4; ++q) {
                float* d = as_w + (q * 4) * LDA + tid;
                d[0 * LDA] = pa[q].x; d[1 * LDA] = pa[q].y;
                d[2 * LDA] = pa[q].z; d[3 * LDA] = pa[q].w;
            }
            float* bs_w = Bs[(kt + 1) & 1];
            #pragma unroll
            for (int q = 0; q < 2; ++q) {
                float* d = bs_w + (bkh * 8 + q * 4) * LDB + brow;
                d[0 * LDB] = pb[q].x; d[1 * LDB] = pb[q].y;
                d[2 * LDB] = pb[q].z; d[3 * LDB] = pb[q].w;
            }
        }
        __syncthreads();
    }

    // epilogue: float4 stores of the partial
    float* cp = Cp + (long)z * TOKENS * NEXPERT + (long)m0 * NEXPERT + n0 + tc * 8;
    #pragma unroll
    for (int i = 0; i < 8; ++i) {
        int row = tr * 8 + i;
        *(float4*)(cp + (long)row * NEXPERT)     = make_float4(acc[i][0], acc[i][1], acc[i][2], acc[i][3]);
        *(float4*)(cp + (long)row * NEXPERT + 4) = make_float4(acc[i][4], acc[i][5], acc[i][6], acc[i][7]);
    }
}

// ---------------- fused reduce + routing ----------------
#define RT_TOK 32
#define SLD    260   // padded stride: phase-2 reads 4-way aliased instead of 32-way

__device__ __forceinline__ float sigmoid_acc(float x) {
    return 1.0f / (1.0f + expf(-x));   // accurate expf: top-k ordering must match ref
}

__global__ __launch_bounds__(256)
void route_reduce(const float* __restrict__ P0,
                  const float* __restrict__ P1,
                  int two,
                  const float* __restrict__ bias,
                  float* __restrict__ out_logits,
                  float* __restrict__ out_idx,
                  float* __restrict__ out_w)
{
    __shared__ float sv[RT_TOK][SLD];       // v = sigmoid(logit) + bias
    __shared__ float gsum[RT_TOK][9];       // group scores (pad 9)

    const int tid = threadIdx.x;
    const int tt  = tid >> 3;   // token in block
    const int g   = tid & 7;    // group
    const long t  = (long)blockIdx.x * RT_TOK + tt;

    // ---- phase 1: logits reduce, sigmoid once, per-group top-2 ----
    {
        const float* p0 = P0 + t * NEXPERT + g * GSIZE;
        const float* p1 = P1 + t * NEXPERT + g * GSIZE;
        const float* bp = bias + g * GSIZE;
        float*       lo = out_logits + t * NEXPERT + g * GSIZE;
        float*       svp = &sv[tt][g * GSIZE];

        float m1 = -INFINITY, m2 = -INFINITY;
        #pragma unroll
        for (int j4 = 0; j4 < GSIZE / 4; ++j4) {
            float4 l = *(const float4*)(p0 + j4 * 4);
            if (two) {
                float4 l1 = *(const float4*)(p1 + j4 * 4);
                l.x += l1.x; l.y += l1.y; l.z += l1.z; l.w += l1.w;
            }
            *(float4*)(lo + j4 * 4) = l;
            float4 b = *(const float4*)(bp + j4 * 4);
            float4 v = make_float4(sigmoid_acc(l.x) + b.x, sigmoid_acc(l.y) + b.y,
                                   sigmoid_acc(l.z) + b.z, sigmoid_acc(l.w) + b.w);
            *(float4*)(svp + j4 * 4) = v;
            float vv[4] = {v.x, v.y, v.z, v.w};
            #pragma unroll
            for (int c = 0; c < 4; ++c) {
                float x = vv[c];
                if (x > m1) { m2 = m1; m1 = x; }
                else if (x > m2) { m2 = x; }
            }
        }
        gsum[tt][g] = m1 + m2;
    }
    __syncthreads();

    // ---- phase 2: one worker lane per token ----
    if (tid < RT_TOK) {
        const int tk = tid;
        const long tok = (long)blockIdx.x * RT_TOK + tk;

        float gs[NGROUP];
        #pragma unroll
        for (int gg = 0; gg < NGROUP; ++gg) gs[gg] = gsum[tk][gg];

        unsigned selmask = 0;
        #pragma unroll
        for (int r = 0; r < TOPKG; ++r) {
            float best = -INFINITY; int bi = 0;
            #pragma unroll
            for (int gg = 0; gg < NGROUP; ++gg) {
                bool taken = (selmask >> gg) & 1u;
                if (!taken && gs[gg] > best) { best = gs[gg]; bi = gg; }
            }
            selmask |= 1u << bi;
        }

        float rv[TOPK]; int ri[TOPK];
        #pragma unroll
        for (int k = 0; k < TOPK; ++k) { rv[k] = -INFINITY; ri[k] = 0; }

        for (int gg = 0; gg < NGROUP; ++gg) {
            if (!((selmask >> gg) & 1u)) continue;
            for (int j = 0; j < GSIZE; ++j) {
                int e = gg * GSIZE + j;
                float v = sv[tk][e];
                if (v > rv[TOPK - 1]) {
                    rv[TOPK - 1] = v; ri[TOPK - 1] = e;
                    #pragma unroll
                    for (int q = TOPK - 1; q > 0; --q) {
                        if (rv[q] > rv[q - 1]) {
                            float tv = rv[q]; rv[q] = rv[q - 1]; rv[q - 1] = tv;
                            int   ti = ri[q]; ri[q] = ri[q - 1]; ri[q - 1] = ti;
                        }
                    }
                }
            }
        }

        // weights use p = v - bias (exact recover; bias is fp32-added once)
        float pv[TOPK]; float sum = 0.0f;
        #pragma unroll
        for (int k = 0; k < TOPK; ++k) { pv[k] = rv[k] - bias[ri[k]]; sum += pv[k]; }
        float denom = sum + 1e-20f;

        #pragma unroll
        for (int k = 0; k < TOPK; ++k) {
            out_idx[tok * TOPK + k] = (float)ri[k];
            out_w[tok * TOPK + k]   = pv[k] / denom * ROUTED_SCALING;
        }
    }
}

// ---------------- launch ----------------
extern "C" void kernel_launch(void* const* d_in, const int* in_sizes, int n_in,
                              void* d_out, int out_size, void* d_ws, size_t ws_size,
                              hipStream_t stream) {
    const float* hidden = (const float*)d_in[0];
    const float* gate_w = (const float*)d_in[1];
    const float* bias   = (const float*)d_in[2];

    float* out = (float*)d_out;
    float* out_idx    = out;
    float* out_w      = out + (long)TOKENS * TOPK;
    float* out_logits = out + (long)TOKENS * TOPK * 2;

    const size_t part_bytes = (size_t)2 * TOKENS * NEXPERT * sizeof(float);
    if (ws_size >= part_bytes) {
        float* part = (float*)d_ws;
        gemm_part<<<dim3(NEXPERT / BN, TOKENS / BM, 2), GTHREADS, 0, stream>>>(
            hidden, gate_w, part, 2);
        route_reduce<<<TOKENS / RT_TOK, 256, 0, stream>>>(
            part, part + (long)TOKENS * NEXPERT, 1, bias, out_logits, out_idx, out_w);
    } else {
        // fallback: single-K directly into out_logits, route re-reads/rewrites it
        gemm_part<<<dim3(NEXPERT / BN, TOKENS / BM, 1), GTHREADS, 0, stream>>>(
            hidden, gate_w, out_logits, 1);
        route_reduce<<<TOKENS / RT_TOK, 256, 0, stream>>>(
            out_logits, out_logits, 0, bias, out_logits, out_idx, out_w);
    }
}

// Round 3
// 2789.087 us; speedup vs baseline: 1.2414x; 1.2414x over previous
//
#include <hip/hip_runtime.h>
#include <math.h>

#define TOKENS  16384
#define HIDDEN  4096
#define NEXPERT 256
#define NGROUP  8
#define GSIZE   32
#define TOPKG   4
#define TOPK    8
#define ROUTED_SCALING 2.5f

// ---------------- GEMM (split-K): Cz = A @ B^T over K-slice z ----------------
// 128x128 block tile, BK=16, 256 threads, 8x8 micro-tile, double-buffered LDS.
// Register budget is deliberately ~110 live VGPRs: the round-2 failure was the
// compiler pinning 128 regs and spilling a 64-reg temp array to scratch
// (WRITE_SIZE 8.7 GB). No temp accumulators here; accuracy comes from split-K.
#define BM 128
#define BN 128
#define BK 16
#define LDT 132   // leading dim: staging writes + fragment reads both 2-way bank-aliased (free)
#define GTHREADS 256

__global__ __launch_bounds__(GTHREADS, 2) __attribute__((amdgpu_waves_per_eu(2, 4)))
void gemm_part(const float* __restrict__ A,   // [TOKENS, HIDDEN]
               const float* __restrict__ B,   // [NEXPERT, HIDDEN]
               float* __restrict__ C0, float* __restrict__ C1,
               float* __restrict__ C2, float* __restrict__ C3,
               int ksplit)
{
    __shared__ float As[2][BK * LDT];   // As[k][m]
    __shared__ float Bs[2][BK * LDT];   // Bs[k][n]

    const int tid = threadIdx.x;
    const int n0  = blockIdx.x * BN;
    const int m0  = blockIdx.y * BM;
    const int z   = blockIdx.z;
    const int kbase = z * (HIDDEN / ksplit);
    const int NKT   = (HIDDEN / ksplit) / BK;

    // staging: thread owns one row (m or n) and one 8-k half -> 2 float4 global
    // loads each for A and B; transpose writes are 2-way bank-aliased (free).
    const int srow = tid >> 1;   // 0..127
    const int skh  = tid & 1;    // 0/1
    const float* Ag = A + (long)(m0 + srow) * HIDDEN + kbase + skh * 8;
    const float* Bg = B + (long)(n0 + srow) * HIDDEN + kbase + skh * 8;

    // compute: wave-tiled 2D map. wave (wr,wc) owns a 64x64 quadrant; lane
    // (lr,lc) = (lane&7, lane>>3) -> LDS fragment reads are 8-lane broadcast
    // + 2-way alias = conflict-free.
    const int wave = tid >> 6;
    const int lane = tid & 63;
    const int row0 = (wave & 1) * 64 + (lane & 7) * 8;
    const int col0 = (wave >> 1) * 64 + (lane >> 3) * 8;

    float4 pa0, pa1, pb0, pb1;
    pa0 = *(const float4*)(Ag);      pa1 = *(const float4*)(Ag + 4);
    pb0 = *(const float4*)(Bg);      pb1 = *(const float4*)(Bg + 4);

    // stage tile 0 -> buffer 0
    {
        float* as = As[0];
        float* bs = Bs[0];
        float va[8] = {pa0.x, pa0.y, pa0.z, pa0.w, pa1.x, pa1.y, pa1.z, pa1.w};
        float vb[8] = {pb0.x, pb0.y, pb0.z, pb0.w, pb1.x, pb1.y, pb1.z, pb1.w};
        #pragma unroll
        for (int j = 0; j < 8; ++j) {
            as[(skh * 8 + j) * LDT + srow] = va[j];
            bs[(skh * 8 + j) * LDT + srow] = vb[j];
        }
    }
    __syncthreads();

    float acc[8][8] = {};

    for (int kt = 0; kt < NKT; ++kt) {
        const int cur = kt & 1;

        // issue next tile's global loads (in flight through the compute)
        if (kt + 1 < NKT) {
            const float* ag = Ag + (kt + 1) * BK;
            const float* bg = Bg + (kt + 1) * BK;
            pa0 = *(const float4*)(ag);  pa1 = *(const float4*)(ag + 4);
            pb0 = *(const float4*)(bg);  pb1 = *(const float4*)(bg + 4);
        }

        // compute current tile
        const float* as = As[cur];
        const float* bs = Bs[cur];
        #pragma unroll
        for (int k = 0; k < BK; ++k) {
            float4 a0 = *(const float4*)(as + k * LDT + row0);
            float4 a1 = *(const float4*)(as + k * LDT + row0 + 4);
            float4 b0 = *(const float4*)(bs + k * LDT + col0);
            float4 b1 = *(const float4*)(bs + k * LDT + col0 + 4);
            float av[8] = {a0.x, a0.y, a0.z, a0.w, a1.x, a1.y, a1.z, a1.w};
            float bv[8] = {b0.x, b0.y, b0.z, b0.w, b1.x, b1.y, b1.z, b1.w};
            #pragma unroll
            for (int i = 0; i < 8; ++i)
                #pragma unroll
                for (int j = 0; j < 8; ++j)
                    acc[i][j] = fmaf(av[i], bv[j], acc[i][j]);
        }

        // stage next tile into the other buffer; single barrier per tile
        if (kt + 1 < NKT) {
            float* asw = As[cur ^ 1];
            float* bsw = Bs[cur ^ 1];
            float va[8] = {pa0.x, pa0.y, pa0.z, pa0.w, pa1.x, pa1.y, pa1.z, pa1.w};
            float vb[8] = {pb0.x, pb0.y, pb0.z, pb0.w, pb1.x, pb1.y, pb1.z, pb1.w};
            #pragma unroll
            for (int j = 0; j < 8; ++j) {
                asw[(skh * 8 + j) * LDT + srow] = va[j];
                bsw[(skh * 8 + j) * LDT + srow] = vb[j];
            }
        }
        __syncthreads();
    }

    // epilogue
    float* Cz = (z == 0) ? C0 : (z == 1) ? C1 : (z == 2) ? C2 : C3;
    float* cp = Cz + (long)(m0 + row0) * NEXPERT + n0 + col0;
    #pragma unroll
    for (int i = 0; i < 8; ++i) {
        *(float4*)(cp + (long)i * NEXPERT)     = make_float4(acc[i][0], acc[i][1], acc[i][2], acc[i][3]);
        *(float4*)(cp + (long)i * NEXPERT + 4) = make_float4(acc[i][4], acc[i][5], acc[i][6], acc[i][7]);
    }
}

// ---------------- fused reduce + routing ----------------
#define RT_TOK 32
#define SLD    260

__device__ __forceinline__ float sigmoid_acc(float x) {
    return 1.0f / (1.0f + expf(-x));   // accurate expf: top-k ordering must match ref
}

__global__ __launch_bounds__(256)
void route_reduce(const float* __restrict__ P0, const float* __restrict__ P1,
                  const float* __restrict__ P2, const float* __restrict__ P3,
                  int ks,
                  const float* __restrict__ bias,
                  float* __restrict__ out_logits,
                  float* __restrict__ out_idx,
                  float* __restrict__ out_w)
{
    __shared__ float sv[RT_TOK][SLD];
    __shared__ float gsum[RT_TOK][9];

    const int tid = threadIdx.x;
    const int tt  = tid >> 3;
    const int g   = tid & 7;
    const long t  = (long)blockIdx.x * RT_TOK + tt;

    // phase 1: reduce partials, sigmoid once, per-group top-2
    {
        const long off = t * NEXPERT + g * GSIZE;
        const float* bp  = bias + g * GSIZE;
        float*       lo  = out_logits + off;
        float*       svp = &sv[tt][g * GSIZE];

        float m1 = -INFINITY, m2 = -INFINITY;
        #pragma unroll
        for (int j4 = 0; j4 < GSIZE / 4; ++j4) {
            float4 l = *(const float4*)(P0 + off + j4 * 4);
            if (ks > 1) {
                float4 l1 = *(const float4*)(P1 + off + j4 * 4);
                l.x += l1.x; l.y += l1.y; l.z += l1.z; l.w += l1.w;
            }
            if (ks > 2) {
                float4 l2 = *(const float4*)(P2 + off + j4 * 4);
                float4 l3 = *(const float4*)(P3 + off + j4 * 4);
                l.x += l2.x; l.y += l2.y; l.z += l2.z; l.w += l2.w;
                l.x += l3.x; l.y += l3.y; l.z += l3.z; l.w += l3.w;
            }
            *(float4*)(lo + j4 * 4) = l;
            float4 b = *(const float4*)(bp + j4 * 4);
            float4 v = make_float4(sigmoid_acc(l.x) + b.x, sigmoid_acc(l.y) + b.y,
                                   sigmoid_acc(l.z) + b.z, sigmoid_acc(l.w) + b.w);
            *(float4*)(svp + j4 * 4) = v;
            float vv[4] = {v.x, v.y, v.z, v.w};
            #pragma unroll
            for (int c = 0; c < 4; ++c) {
                float x = vv[c];
                if (x > m1) { m2 = m1; m1 = x; }
                else if (x > m2) { m2 = x; }
            }
        }
        gsum[tt][g] = m1 + m2;
    }
    __syncthreads();

    // phase 2: one worker lane per token
    if (tid < RT_TOK) {
        const int tk = tid;
        const long tok = (long)blockIdx.x * RT_TOK + tk;

        float gs[NGROUP];
        #pragma unroll
        for (int gg = 0; gg < NGROUP; ++gg) gs[gg] = gsum[tk][gg];

        unsigned selmask = 0;
        #pragma unroll
        for (int r = 0; r < TOPKG; ++r) {
            float best = -INFINITY; int bi = 0;
            #pragma unroll
            for (int gg = 0; gg < NGROUP; ++gg) {
                bool taken = (selmask >> gg) & 1u;
                if (!taken && gs[gg] > best) { best = gs[gg]; bi = gg; }
            }
            selmask |= 1u << bi;
        }

        float rv[TOPK]; int ri[TOPK];
        #pragma unroll
        for (int k = 0; k < TOPK; ++k) { rv[k] = -INFINITY; ri[k] = 0; }

        for (int gg = 0; gg < NGROUP; ++gg) {
            if (!((selmask >> gg) & 1u)) continue;
            for (int j = 0; j < GSIZE; ++j) {
                int e = gg * GSIZE + j;
                float v = sv[tk][e];
                if (v > rv[TOPK - 1]) {
                    rv[TOPK - 1] = v; ri[TOPK - 1] = e;
                    #pragma unroll
                    for (int q = TOPK - 1; q > 0; --q) {
                        if (rv[q] > rv[q - 1]) {
                            float tv = rv[q]; rv[q] = rv[q - 1]; rv[q - 1] = tv;
                            int   ti = ri[q]; ri[q] = ri[q - 1]; ri[q - 1] = ti;
                        }
                    }
                }
            }
        }

        float pv[TOPK]; float sum = 0.0f;
        #pragma unroll
        for (int k = 0; k < TOPK; ++k) { pv[k] = rv[k] - bias[ri[k]]; sum += pv[k]; }
        float denom = sum + 1e-20f;

        #pragma unroll
        for (int k = 0; k < TOPK; ++k) {
            out_idx[tok * TOPK + k] = (float)ri[k];
            out_w[tok * TOPK + k]   = pv[k] / denom * ROUTED_SCALING;
        }
    }
}

// ---------------- launch ----------------
extern "C" void kernel_launch(void* const* d_in, const int* in_sizes, int n_in,
                              void* d_out, int out_size, void* d_ws, size_t ws_size,
                              hipStream_t stream) {
    const float* hidden = (const float*)d_in[0];
    const float* gate_w = (const float*)d_in[1];
    const float* bias   = (const float*)d_in[2];

    float* out = (float*)d_out;
    float* out_idx    = out;
    float* out_w      = out + (long)TOKENS * TOPK;
    float* out_logits = out + (long)TOKENS * TOPK * 2;

    const size_t PB = (size_t)TOKENS * NEXPERT * sizeof(float);   // 16 MB per partial
    float* wsf = (float*)d_ws;
    const long PE = (long)TOKENS * NEXPERT;

    int ks;
    float *c0, *c1, *c2, *c3;
    if (ws_size >= 4 * PB)      { ks = 4; c0 = wsf; c1 = wsf + PE; c2 = wsf + 2*PE; c3 = wsf + 3*PE; }
    else if (ws_size >= 3 * PB) { ks = 4; c0 = out_logits; c1 = wsf; c2 = wsf + PE; c3 = wsf + 2*PE; }
    else if (ws_size >= 2 * PB) { ks = 2; c0 = wsf; c1 = wsf + PE; c2 = c0; c3 = c0; }
    else if (ws_size >= 1 * PB) { ks = 2; c0 = out_logits; c1 = wsf; c2 = c0; c3 = c0; }
    else                        { ks = 1; c0 = out_logits; c1 = c0; c2 = c0; c3 = c0; }

    gemm_part<<<dim3(NEXPERT / BN, TOKENS / BM, ks), GTHREADS, 0, stream>>>(
        hidden, gate_w, c0, c1, c2, c3, ks);

    route_reduce<<<TOKENS / RT_TOK, 256, 0, stream>>>(
        c0, c1, c2, c3, ks, bias, out_logits, out_idx, out_w);
}

// Round 4
// 878.081 us; speedup vs baseline: 3.9432x; 3.1763x over previous
//
#include <hip/hip_runtime.h>
#include <math.h>

#define TOKENS  16384
#define HIDDEN  4096
#define NEXPERT 256
#define NGROUP  8
#define GSIZE   32
#define TOPKG   4
#define TOPK    8
#define RSCALE  2.5f

// One fused kernel: block = 64 tokens x ALL 256 experts, full K, routing in
// epilogue. Register policy: waves_per_eu(1,1) -> 512-VGPR budget, no spill
// possible (rounds 2/3 died to the allocator capping at 128 and spilling the
// 64-reg accumulator: WRITE_SIZE 6.9-8.7 GB of scratch traffic).
#define BM  64
#define BK  16
#define LDA 68    // A-tile leading pad: staging writes / frag reads 2-way aliased (free)
#define LDB 260   // B-tile leading pad

__device__ __forceinline__ float sigmoid_acc(float x) {
    return 1.0f / (1.0f + expf(-x));   // accurate expf: top-k order must match ref
}

__global__ __launch_bounds__(256, 1) __attribute__((amdgpu_waves_per_eu(1, 1)))
void moe_gate_fused(const float* __restrict__ A,      // [TOKENS, HIDDEN]
                    const float* __restrict__ B,      // [NEXPERT, HIDDEN]
                    const float* __restrict__ bias,   // [NEXPERT]
                    float* __restrict__ out_idx,
                    float* __restrict__ out_w,
                    float* __restrict__ out_logits)
{
    __shared__ float As[2][BK * LDA];          // As[k][m], 64 rows
    __shared__ float Bs[2][BK * LDB];          // Bs[k][n], 256 rows
    __shared__ float gsum[BM][NGROUP + 1];

    const int tid = threadIdx.x;
    const int m0  = blockIdx.x * BM;

    // ---- staging map: thread owns (row ar, k-quad kq) ----
    // A: 64x16 tile, 1 float4/thread. B: 256x16 tile, 4 float4/thread
    // (rows p*64+ar). Global loads: 4 consecutive lanes read 64B of one row.
    const int ar = tid >> 2;     // 0..63
    const int kq = tid & 3;      // 0..3
    const float* Ag = A + (long)(m0 + ar) * HIDDEN + kq * 4;
    const float* Bg = B + (long)ar * HIDDEN + kq * 4;

    // ---- compute map: 8x32 thread grid, 8x8 micro-tile ----
    // rows row0..row0+7; cols c0..c0+3 and 128+c0..128+c0+3 (split halves so
    // B-fragment ds_read_b128 lane-addresses stride 16B -> conflict-free).
    const int tr   = tid >> 5;   // 0..7
    const int tc   = tid & 31;   // 0..31
    const int row0 = tr * 8;
    const int c0   = tc * 4;

    float4 pa, pb0, pb1, pb2, pb3;

    // prefetch tile 0
    pa  = *(const float4*)(Ag);
    pb0 = *(const float4*)(Bg + (long)0 * 64 * HIDDEN);
    pb1 = *(const float4*)(Bg + (long)1 * 64 * HIDDEN);
    pb2 = *(const float4*)(Bg + (long)2 * 64 * HIDDEN);
    pb3 = *(const float4*)(Bg + (long)3 * 64 * HIDDEN);

    // stage tile 0 -> buffer 0
    {
        float* as = As[0];
        as[(kq * 4 + 0) * LDA + ar] = pa.x;
        as[(kq * 4 + 1) * LDA + ar] = pa.y;
        as[(kq * 4 + 2) * LDA + ar] = pa.z;
        as[(kq * 4 + 3) * LDA + ar] = pa.w;
        float* bs = Bs[0];
        float vb[4][4] = {{pb0.x,pb0.y,pb0.z,pb0.w},{pb1.x,pb1.y,pb1.z,pb1.w},
                          {pb2.x,pb2.y,pb2.z,pb2.w},{pb3.x,pb3.y,pb3.z,pb3.w}};
        #pragma unroll
        for (int p = 0; p < 4; ++p)
            #pragma unroll
            for (int j = 0; j < 4; ++j)
                bs[(kq * 4 + j) * LDB + p * 64 + ar] = vb[p][j];
    }
    __syncthreads();

    float acc[8][8] = {};

    const int NKT = HIDDEN / BK;   // 256
    for (int kt = 0; kt < NKT; ++kt) {
        const int cur = kt & 1;

        if (kt + 1 < NKT) {
            const int ko = (kt + 1) * BK;
            pa  = *(const float4*)(Ag + ko);
            pb0 = *(const float4*)(Bg + (long)0 * 64 * HIDDEN + ko);
            pb1 = *(const float4*)(Bg + (long)1 * 64 * HIDDEN + ko);
            pb2 = *(const float4*)(Bg + (long)2 * 64 * HIDDEN + ko);
            pb3 = *(const float4*)(Bg + (long)3 * 64 * HIDDEN + ko);
        }

        const float* as = As[cur];
        const float* bs = Bs[cur];
        #pragma unroll
        for (int k = 0; k < BK; ++k) {
            float4 a0 = *(const float4*)(as + k * LDA + row0);       // 32-lane bcast
            float4 a1 = *(const float4*)(as + k * LDA + row0 + 4);
            float4 b0 = *(const float4*)(bs + k * LDB + c0);         // conflict-free
            float4 b1 = *(const float4*)(bs + k * LDB + 128 + c0);
            float av[8] = {a0.x, a0.y, a0.z, a0.w, a1.x, a1.y, a1.z, a1.w};
            float bv[8] = {b0.x, b0.y, b0.z, b0.w, b1.x, b1.y, b1.z, b1.w};
            #pragma unroll
            for (int i = 0; i < 8; ++i)
                #pragma unroll
                for (int j = 0; j < 8; ++j)
                    acc[i][j] = fmaf(av[i], bv[j], acc[i][j]);
        }

        if (kt + 1 < NKT) {
            float* as_w = As[cur ^ 1];
            as_w[(kq * 4 + 0) * LDA + ar] = pa.x;
            as_w[(kq * 4 + 1) * LDA + ar] = pa.y;
            as_w[(kq * 4 + 2) * LDA + ar] = pa.z;
            as_w[(kq * 4 + 3) * LDA + ar] = pa.w;
            float* bs_w = Bs[cur ^ 1];
            float vb[4][4] = {{pb0.x,pb0.y,pb0.z,pb0.w},{pb1.x,pb1.y,pb1.z,pb1.w},
                              {pb2.x,pb2.y,pb2.z,pb2.w},{pb3.x,pb3.y,pb3.z,pb3.w}};
            #pragma unroll
            for (int p = 0; p < 4; ++p)
                #pragma unroll
                for (int j = 0; j < 4; ++j)
                    bs_w[(kq * 4 + j) * LDB + p * 64 + ar] = vb[p][j];
        }
        __syncthreads();
    }

    // ---- epilogue: write logits (coalesced float4) ----
    #pragma unroll
    for (int i = 0; i < 8; ++i) {
        long row = m0 + row0 + i;
        *(float4*)(out_logits + row * NEXPERT + c0)       = make_float4(acc[i][0], acc[i][1], acc[i][2], acc[i][3]);
        *(float4*)(out_logits + row * NEXPERT + 128 + c0) = make_float4(acc[i][4], acc[i][5], acc[i][6], acc[i][7]);
    }
    __syncthreads();   // barrier drains vmcnt -> this block's logits visible via its L2

    // ---- routing phase A: per (token, group) top-2 of sigmoid(logit)+bias ----
    for (int task = tid; task < BM * NGROUP; task += 256) {
        const int tt = task >> 3;
        const int g  = task & 7;
        const float* lg = out_logits + (long)(m0 + tt) * NEXPERT + g * GSIZE;
        const float* bp = bias + g * GSIZE;
        float m1 = -INFINITY, m2 = -INFINITY;
        #pragma unroll
        for (int j4 = 0; j4 < GSIZE / 4; ++j4) {
            float4 l = *(const float4*)(lg + j4 * 4);
            float4 b = *(const float4*)(bp + j4 * 4);
            float vv[4] = {sigmoid_acc(l.x) + b.x, sigmoid_acc(l.y) + b.y,
                           sigmoid_acc(l.z) + b.z, sigmoid_acc(l.w) + b.w};
            #pragma unroll
            for (int c = 0; c < 4; ++c) {
                float x = vv[c];
                if (x > m1) { m2 = m1; m1 = x; }
                else if (x > m2) { m2 = x; }
            }
        }
        gsum[tt][g] = m1 + m2;
    }
    __syncthreads();

    // ---- routing phase B: one worker per token ----
    if (tid < BM) {
        const long tok = m0 + tid;
        const float* lg = out_logits + tok * NEXPERT;

        float gs[NGROUP];
        #pragma unroll
        for (int g = 0; g < NGROUP; ++g) gs[g] = gsum[tid][g];

        unsigned selmask = 0;
        #pragma unroll
        for (int r = 0; r < TOPKG; ++r) {
            float best = -INFINITY; int bi = 0;
            #pragma unroll
            for (int g = 0; g < NGROUP; ++g) {
                bool taken = (selmask >> g) & 1u;
                if (!taken && gs[g] > best) { best = gs[g]; bi = g; }
            }
            selmask |= 1u << bi;
        }

        float rv[TOPK]; int ri[TOPK];
        #pragma unroll
        for (int k = 0; k < TOPK; ++k) { rv[k] = -INFINITY; ri[k] = 0; }

        for (int g = 0; g < NGROUP; ++g) {
            if (!((selmask >> g) & 1u)) continue;
            #pragma unroll 4
            for (int j = 0; j < GSIZE; ++j) {
                int e = g * GSIZE + j;
                float v = sigmoid_acc(lg[e]) + bias[e];
                if (v > rv[TOPK - 1]) {
                    rv[TOPK - 1] = v; ri[TOPK - 1] = e;
                    #pragma unroll
                    for (int q = TOPK - 1; q > 0; --q) {
                        if (rv[q] > rv[q - 1]) {
                            float tv = rv[q]; rv[q] = rv[q - 1]; rv[q - 1] = tv;
                            int   ti = ri[q]; ri[q] = ri[q - 1]; ri[q - 1] = ti;
                        }
                    }
                }
            }
        }

        float pv[TOPK]; float sum = 0.0f;
        #pragma unroll
        for (int k = 0; k < TOPK; ++k) { pv[k] = rv[k] - bias[ri[k]]; sum += pv[k]; }
        float denom = sum + 1e-20f;

        #pragma unroll
        for (int k = 0; k < TOPK; ++k) {
            out_idx[tok * TOPK + k] = (float)ri[k];
            out_w[tok * TOPK + k]   = pv[k] / denom * RSCALE;
        }
    }
}

// ---------------- launch ----------------
extern "C" void kernel_launch(void* const* d_in, const int* in_sizes, int n_in,
                              void* d_out, int out_size, void* d_ws, size_t ws_size,
                              hipStream_t stream) {
    const float* hidden = (const float*)d_in[0];
    const float* gate_w = (const float*)d_in[1];
    const float* bias   = (const float*)d_in[2];

    float* out = (float*)d_out;
    float* out_idx    = out;
    float* out_w      = out + (long)TOKENS * TOPK;
    float* out_logits = out + (long)TOKENS * TOPK * 2;

    moe_gate_fused<<<TOKENS / BM, 256, 0, stream>>>(
        hidden, gate_w, bias, out_idx, out_w, out_logits);
}